// Round 7
// baseline (247.459 us; speedup 1.0000x reference)
//
#include <hip/hip_runtime.h>
#include <hip/hip_bf16.h>
#include <hip/hip_cooperative_groups.h>

namespace cg = cooperative_groups;

#define NN 8192
#define DD 256
#define EE (NN - 1)
#define NB 512     // blocks (2 per CU, exactly co-resident)
#define NT 256

typedef __attribute__((ext_vector_type(8))) short bf16x8;
typedef __attribute__((ext_vector_type(4))) float f32x4;

__device__ inline unsigned short f2bf(float f) {
  return __builtin_bit_cast(unsigned short, __float2bfloat16(f));
}

// ---------------------------------------------------------------------------
// Single cooperative kernel, 4 phases separated by grid.sync():
//  P0: blocks 0..63  : partial u,v  (u = W^T a[:D], v = W^T a[D:], f32 exact)
//      blocks 64..95 : inv[i] = -1
//  P1: block 0       : reduce 64 partials -> u, v   (fixed order, deterministic)
//      blocks 96..127: inv[gov[e]] = e
//  P2: all blocks    : per row j: s = x[j]·u + x[d]·v (wave-reduced, f32 exact)
//                      y[j] = bf16( x[gov[j-1]] + coef(s)·x[d] )
//  P3: all blocks    : out = leaky_relu( y @ bf16(W)^T )  via mfma 16x16x32
// ---------------------------------------------------------------------------
#define BM 64
#define BN 64
#define LDAB 40

__global__ __launch_bounds__(NT, 2) void fused(
    const float* __restrict__ x, const float* __restrict__ W,
    const float* __restrict__ a, const int* __restrict__ gov,
    float* __restrict__ pu, float* __restrict__ pv,
    float* __restrict__ u, float* __restrict__ v,
    int* __restrict__ inv, unsigned short* __restrict__ y,
    float* __restrict__ out) {
  cg::grid_group grid = cg::this_grid();
  const int blk = blockIdx.x, t = threadIdx.x;

  __shared__ unsigned short As[BM][LDAB];
  __shared__ unsigned short Bs[BN][LDAB];

  // ---------------- phase 0 ----------------
  if (blk < 64) {
    float su = 0.f, sv = 0.f;
    const int j0 = blk * 4;
#pragma unroll
    for (int jj = 0; jj < 4; ++jj) {
      float w = W[(size_t)(j0 + jj) * DD + t];   // coalesced over t
      su = fmaf(a[j0 + jj], w, su);
      sv = fmaf(a[DD + j0 + jj], w, sv);
    }
    pu[blk * DD + t] = su;
    pv[blk * DD + t] = sv;
  } else if (blk < 96) {
    inv[(blk - 64) * 256 + t] = -1;
  }
  grid.sync();

  // ---------------- phase 1 ----------------
  if (blk == 0) {
    float su = 0.f, sv = 0.f;
#pragma unroll 8
    for (int b = 0; b < 64; ++b) {
      su += pu[b * DD + t];
      sv += pv[b * DD + t];
    }
    u[t] = su;
    v[t] = sv;
  } else if (blk >= 96 && blk < 128) {
    const int e = (blk - 96) * 256 + t;
    if (e < EE) inv[gov[e]] = e;
  }
  grid.sync();

  // ---------------- phase 2 ----------------
  {
    const int wid = t >> 6, lane = t & 63;
    const float4 uv = *(const float4*)&u[lane * 4];
    const float4 vv = *(const float4*)&v[lane * 4];
#pragma unroll
    for (int r = 0; r < 4; ++r) {
      const int j = blk * 16 + wid * 4 + r;
      float4 h = make_float4(0.f, 0.f, 0.f, 0.f);
      if (j > 0) {
        const int g = gov[j - 1];
        h = *(const float4*)&x[(size_t)g * DD + lane * 4];
      }
      const int e2 = inv[j];
      if (e2 >= 0) {
        const int d = e2 + 1;
        const float4 xj = *(const float4*)&x[(size_t)j * DD + lane * 4];
        const float4 xd = *(const float4*)&x[(size_t)d * DD + lane * 4];
        float s = xj.x * uv.x + xj.y * uv.y + xj.z * uv.z + xj.w * uv.w +
                  xd.x * vv.x + xd.y * vv.y + xd.z * vv.z + xd.w * vv.w;
#pragma unroll
        for (int off = 32; off; off >>= 1) s += __shfl_xor(s, off);
        const float coef = (s > 0.f) ? 1.f : (1.f / 8192.f);
        h.x = fmaf(coef, xd.x, h.x);
        h.y = fmaf(coef, xd.y, h.y);
        h.z = fmaf(coef, xd.z, h.z);
        h.w = fmaf(coef, xd.w, h.w);
      }
      ushort4 pk;
      pk.x = f2bf(h.x); pk.y = f2bf(h.y); pk.z = f2bf(h.z); pk.w = f2bf(h.w);
      *(ushort4*)&y[(size_t)j * DD + lane * 4] = pk;
    }
  }
  grid.sync();

  // ---------------- phase 3: gemm ----------------
  {
    const int bm = (blk & 127) * BM, bn = (blk >> 7) * BN;
    const int lane = t & 63, wid = t >> 6;
    const int wr = wid >> 1, wc = wid & 1;     // wave -> 32x32 subtile
    const int l15 = lane & 15, l4 = lane >> 4;
    const int srow = t >> 2, sseg = t & 3;     // stage: 4 thr/row

    f32x4 acc[2][2] = {};

    for (int k0 = 0; k0 < DD; k0 += 32) {
      {  // A: bf16 y, 64 rows x 32 shorts
        ushort4 w0 = *(const ushort4*)&y[(size_t)(bm + srow) * DD + k0 + sseg * 8];
        ushort4 w1 = *(const ushort4*)&y[(size_t)(bm + srow) * DD + k0 + sseg * 8 + 4];
        *(ushort4*)&As[srow][sseg * 8] = w0;
        *(ushort4*)&As[srow][sseg * 8 + 4] = w1;
      }
      {  // B: f32 W -> bf16, 64 rows x 32 floats
        const float* src = &W[(size_t)(bn + srow) * DD + k0 + sseg * 8];
        float4 f0 = *(const float4*)src;
        float4 f1 = *(const float4*)(src + 4);
        ushort4 p0, p1;
        p0.x = f2bf(f0.x); p0.y = f2bf(f0.y); p0.z = f2bf(f0.z); p0.w = f2bf(f0.w);
        p1.x = f2bf(f1.x); p1.y = f2bf(f1.y); p1.z = f2bf(f1.z); p1.w = f2bf(f1.w);
        *(ushort4*)&Bs[srow][sseg * 8] = p0;
        *(ushort4*)&Bs[srow][sseg * 8 + 4] = p1;
      }
      __syncthreads();

      bf16x8 af[2], bfr[2];
#pragma unroll
      for (int mf = 0; mf < 2; ++mf)
        af[mf] = *(const bf16x8*)&As[wr * 32 + mf * 16 + l15][l4 * 8];
#pragma unroll
      for (int nf = 0; nf < 2; ++nf)
        bfr[nf] = *(const bf16x8*)&Bs[wc * 32 + nf * 16 + l15][l4 * 8];
#pragma unroll
      for (int mf = 0; mf < 2; ++mf)
#pragma unroll
        for (int nf = 0; nf < 2; ++nf)
          acc[mf][nf] = __builtin_amdgcn_mfma_f32_16x16x32_bf16(
              af[mf], bfr[nf], acc[mf][nf], 0, 0, 0);
      __syncthreads();
    }

    // C/D layout (m89): col = lane&15, row = (lane>>4)*4 + reg; fused LeakyReLU
#pragma unroll
    for (int mf = 0; mf < 2; ++mf)
#pragma unroll
      for (int nf = 0; nf < 2; ++nf)
#pragma unroll
        for (int r = 0; r < 4; ++r) {
          const int row = bm + wr * 32 + mf * 16 + l4 * 4 + r;
          const int col = bn + wc * 32 + nf * 16 + l15;
          float hval = acc[mf][nf][r];
          out[(size_t)row * DD + col] = (hval >= 0.f) ? hval : 0.2f * hval;
        }
  }
}

extern "C" void kernel_launch(void* const* d_in, const int* in_sizes, int n_in,
                              void* d_out, int out_size, void* d_ws, size_t ws_size,
                              hipStream_t stream) {
  const float* x = (const float*)d_in[0];
  const float* W = (const float*)d_in[1];
  const float* a = (const float*)d_in[2];
  const int* gov = (const int*)d_in[4];

  float* pu = (float*)d_ws;                        // 64 KB
  float* pv = pu + 64 * DD;                        // 64 KB
  float* u  = pv + 64 * DD;                        // 1 KB
  float* v  = u + DD;                              // 1 KB
  int* inv  = (int*)(v + DD);                      // 32 KB
  unsigned short* y = (unsigned short*)(inv + NN); // 4 MB bf16
  float* outp = (float*)d_out;

  void* args[] = {(void*)&x, (void*)&W, (void*)&a, (void*)&gov,
                  (void*)&pu, (void*)&pv, (void*)&u, (void*)&v,
                  (void*)&inv, (void*)&y, (void*)&outp};
  hipLaunchCooperativeKernel((const void*)fused, dim3(NB), dim3(NT), args, 0,
                             stream);
}

// Round 11
// 96.280 us; speedup vs baseline: 2.5702x; 2.5702x over previous
//
#include <hip/hip_runtime.h>
#include <hip/hip_bf16.h>

#define NN 8192
#define DD 256
#define EE (NN - 1)

typedef __attribute__((ext_vector_type(8))) short bf16x8;
typedef __attribute__((ext_vector_type(4))) float f32x4;

__device__ inline unsigned short f2bf(float f) {
  return __builtin_bit_cast(unsigned short, __float2bfloat16(f));
}

// ---------------------------------------------------------------------------
// prep: single block, 1024 threads.
//   inv[i] = -1; inv[gov[e]] = e   (ordered via __syncthreads within the block)
//   u = W^T a[:D], v = W^T a[D:]   (exact f32; carries the sign of s)
// ---------------------------------------------------------------------------
__global__ __launch_bounds__(1024) void prep(
    const float* __restrict__ W, const float* __restrict__ a,
    const int* __restrict__ gov,
    float* __restrict__ u, float* __restrict__ v, int* __restrict__ inv) {
  const int t = threadIdx.x;
  const int k = t & 255, part = t >> 8;

  for (int i = t; i < NN; i += 1024) inv[i] = -1;
  __syncthreads();
  for (int e = t; e < EE; e += 1024) inv[gov[e]] = e;

  float up = 0.f, vp = 0.f;
  const int j0 = part * 64;
#pragma unroll 4
  for (int j = j0; j < j0 + 64; ++j) {
    float w = W[(size_t)j * DD + k];   // coalesced across k
    up = fmaf(a[j], w, up);
    vp = fmaf(a[DD + j], w, vp);
  }
  __shared__ float redu[4][256], redv[4][256];
  redu[part][k] = up; redv[part][k] = vp;
  __syncthreads();
  if (t < 256) {
    u[t] = redu[0][t] + redu[1][t] + redu[2][t] + redu[3][t];
    v[t] = redv[0][t] + redv[1][t] + redv[2][t] + redv[3][t];
  }
}

// ---------------------------------------------------------------------------
// combine (with inline s): one wave per row j.
//   s = x[j]·u + x[d]·v        (f32 exact, wave shfl_xor reduce — same
//                               numerics as the verified coop phase 2)
//   y[j] = bf16( (j>0 ? x[gov[j-1]] : 0) + (inv[j]>=0 ? coef(s)·x[d] : 0) )
// ---------------------------------------------------------------------------
__global__ __launch_bounds__(256) void combine(
    const float* __restrict__ x, const float* __restrict__ u,
    const float* __restrict__ v, const int* __restrict__ gov,
    const int* __restrict__ inv, unsigned short* __restrict__ y) {
  const int wid = threadIdx.x >> 6, lane = threadIdx.x & 63;
  const int j = blockIdx.x * 4 + wid;

  const float4 uv = *(const float4*)&u[lane * 4];
  const float4 vv = *(const float4*)&v[lane * 4];

  float4 h = make_float4(0.f, 0.f, 0.f, 0.f);
  if (j > 0) {
    const int g = gov[j - 1];
    h = *(const float4*)&x[(size_t)g * DD + lane * 4];
  }
  const int e2 = inv[j];
  if (e2 >= 0) {
    const int d = e2 + 1;
    const float4 xj = *(const float4*)&x[(size_t)j * DD + lane * 4];
    const float4 xd = *(const float4*)&x[(size_t)d * DD + lane * 4];
    float s = xj.x * uv.x + xj.y * uv.y + xj.z * uv.z + xj.w * uv.w +
              xd.x * vv.x + xd.y * vv.y + xd.z * vv.z + xd.w * vv.w;
#pragma unroll
    for (int off = 32; off; off >>= 1) s += __shfl_xor(s, off);
    const float coef = (s > 0.f) ? 1.f : (1.f / 8192.f);
    h.x = fmaf(coef, xd.x, h.x);
    h.y = fmaf(coef, xd.y, h.y);
    h.z = fmaf(coef, xd.z, h.z);
    h.w = fmaf(coef, xd.w, h.w);
  }
  ushort4 pk;
  pk.x = f2bf(h.x); pk.y = f2bf(h.y); pk.z = f2bf(h.z); pk.w = f2bf(h.w);
  *(ushort4*)&y[(size_t)j * DD + lane * 4] = pk;
}

// ---------------------------------------------------------------------------
// gemm: out = leaky_relu( y_bf16 @ bf16(W)^T ), f32 accum via mfma 16x16x32.
// 64x64 tile, 4 waves (2x2, each 32x32), BK=32, grid 128x4 = 512 blocks.
// LDS rows padded to 40 shorts (80 B): 16B-aligned b128 frags, <=2-way banks.
// ---------------------------------------------------------------------------
#define BM 64
#define BN 64
#define LDAB 40

__global__ __launch_bounds__(256) void gemm_out(
    const unsigned short* __restrict__ Y, const float* __restrict__ W,
    float* __restrict__ out) {
  __shared__ unsigned short As[BM][LDAB];
  __shared__ unsigned short Bs[BN][LDAB];
  const int t = threadIdx.x;
  const int bm = blockIdx.x * BM, bn = blockIdx.y * BN;
  const int lane = t & 63, wid = t >> 6;
  const int wr = wid >> 1, wc = wid & 1;      // wave -> 32x32 subtile
  const int l15 = lane & 15, l4 = lane >> 4;
  const int srow = t >> 2, sseg = t & 3;      // stage: 4 thr/row

  f32x4 acc[2][2] = {};

  for (int k0 = 0; k0 < DD; k0 += 32) {
    {  // A: bf16 y, 64 rows x 32 shorts
      ushort4 w0 = *(const ushort4*)&Y[(size_t)(bm + srow) * DD + k0 + sseg * 8];
      ushort4 w1 = *(const ushort4*)&Y[(size_t)(bm + srow) * DD + k0 + sseg * 8 + 4];
      *(ushort4*)&As[srow][sseg * 8] = w0;
      *(ushort4*)&As[srow][sseg * 8 + 4] = w1;
    }
    {  // B: f32 W -> bf16, 64 rows x 32 floats
      const float* src = &W[(size_t)(bn + srow) * DD + k0 + sseg * 8];
      float4 f0 = *(const float4*)src;
      float4 f1 = *(const float4*)(src + 4);
      ushort4 p0, p1;
      p0.x = f2bf(f0.x); p0.y = f2bf(f0.y); p0.z = f2bf(f0.z); p0.w = f2bf(f0.w);
      p1.x = f2bf(f1.x); p1.y = f2bf(f1.y); p1.z = f2bf(f1.z); p1.w = f2bf(f1.w);
      *(ushort4*)&Bs[srow][sseg * 8] = p0;
      *(ushort4*)&Bs[srow][sseg * 8 + 4] = p1;
    }
    __syncthreads();

    bf16x8 af[2], bfr[2];
#pragma unroll
    for (int mf = 0; mf < 2; ++mf)
      af[mf] = *(const bf16x8*)&As[wr * 32 + mf * 16 + l15][l4 * 8];
#pragma unroll
    for (int nf = 0; nf < 2; ++nf)
      bfr[nf] = *(const bf16x8*)&Bs[wc * 32 + nf * 16 + l15][l4 * 8];
#pragma unroll
    for (int mf = 0; mf < 2; ++mf)
#pragma unroll
      for (int nf = 0; nf < 2; ++nf)
        acc[mf][nf] = __builtin_amdgcn_mfma_f32_16x16x32_bf16(
            af[mf], bfr[nf], acc[mf][nf], 0, 0, 0);
    __syncthreads();
  }

  // C/D layout (m89): col = lane&15, row = (lane>>4)*4 + reg; fused LeakyReLU
#pragma unroll
  for (int mf = 0; mf < 2; ++mf)
#pragma unroll
    for (int nf = 0; nf < 2; ++nf)
#pragma unroll
      for (int r = 0; r < 4; ++r) {
        const int row = bm + wr * 32 + mf * 16 + l4 * 4 + r;
        const int col = bn + wc * 32 + nf * 16 + l15;
        float hval = acc[mf][nf][r];
        out[(size_t)row * DD + col] = (hval >= 0.f) ? hval : 0.2f * hval;
      }
}

extern "C" void kernel_launch(void* const* d_in, const int* in_sizes, int n_in,
                              void* d_out, int out_size, void* d_ws, size_t ws_size,
                              hipStream_t stream) {
  const float* x = (const float*)d_in[0];
  const float* W = (const float*)d_in[1];
  const float* a = (const float*)d_in[2];
  const int* gov = (const int*)d_in[4];

  float* u = (float*)d_ws;                         // 1 KB
  float* v = u + DD;                               // 1 KB
  int* inv = (int*)(v + DD);                       // 32 KB
  unsigned short* y = (unsigned short*)(inv + NN); // 4 MB bf16

  hipLaunchKernelGGL(prep, dim3(1), dim3(1024), 0, stream, W, a, gov, u, v, inv);
  hipLaunchKernelGGL(combine, dim3(NN / 4), dim3(256), 0, stream,
                     x, u, v, gov, inv, y);
  hipLaunchKernelGGL(gemm_out, dim3(NN / BM, DD / BN), dim3(256), 0, stream,
                     y, W, (float*)d_out);
}

// Round 16
// 95.420 us; speedup vs baseline: 2.5934x; 1.0090x over previous
//
#include <hip/hip_runtime.h>
#include <hip/hip_bf16.h>

#define NN 8192
#define DD 256
#define EE (NN - 1)

typedef __attribute__((ext_vector_type(8))) short bf16x8;
typedef __attribute__((ext_vector_type(4))) float f32x4;

__device__ inline unsigned short f2bf(float f) {
  return __builtin_bit_cast(unsigned short, __float2bfloat16(f));
}

// ---------------------------------------------------------------------------
// prep: single block, 1024 threads.
//   inv[i] = -1; inv[gov[e]] = e   (ordered via __syncthreads within the block)
//   u = W^T a[:D], v = W^T a[D:]   (exact f32; carries the sign of s)
// ---------------------------------------------------------------------------
__global__ __launch_bounds__(1024) void prep(
    const float* __restrict__ W, const float* __restrict__ a,
    const int* __restrict__ gov,
    float* __restrict__ u, float* __restrict__ v, int* __restrict__ inv) {
  const int t = threadIdx.x;
  const int k = t & 255, part = t >> 8;

  for (int i = t; i < NN; i += 1024) inv[i] = -1;
  __syncthreads();
  for (int e = t; e < EE; e += 1024) inv[gov[e]] = e;

  float up = 0.f, vp = 0.f;
  const int j0 = part * 64;
#pragma unroll 4
  for (int j = j0; j < j0 + 64; ++j) {
    float w = W[(size_t)j * DD + k];   // coalesced across k
    up = fmaf(a[j], w, up);
    vp = fmaf(a[DD + j], w, vp);
  }
  __shared__ float redu[4][256], redv[4][256];
  redu[part][k] = up; redv[part][k] = vp;
  __syncthreads();
  if (t < 256) {
    u[t] = redu[0][t] + redu[1][t] + redu[2][t] + redu[3][t];
    v[t] = redv[0][t] + redv[1][t] + redv[2][t] + redv[3][t];
  }
}

// ---------------------------------------------------------------------------
// combine (with inline s): one wave per row j.
//   s = x[j]·u + x[d]·v        (f32 exact, wave shfl_xor reduce)
//   y[j] = bf16( (j>0 ? x[gov[j-1]] : 0) + (inv[j]>=0 ? coef(s)·x[d] : 0) )
// ---------------------------------------------------------------------------
__global__ __launch_bounds__(256) void combine(
    const float* __restrict__ x, const float* __restrict__ u,
    const float* __restrict__ v, const int* __restrict__ gov,
    const int* __restrict__ inv, unsigned short* __restrict__ y) {
  const int wid = threadIdx.x >> 6, lane = threadIdx.x & 63;
  const int j = blockIdx.x * 4 + wid;

  const float4 uv = *(const float4*)&u[lane * 4];
  const float4 vv = *(const float4*)&v[lane * 4];

  float4 h = make_float4(0.f, 0.f, 0.f, 0.f);
  if (j > 0) {
    const int g = gov[j - 1];
    h = *(const float4*)&x[(size_t)g * DD + lane * 4];
  }
  const int e2 = inv[j];
  if (e2 >= 0) {
    const int d = e2 + 1;
    const float4 xj = *(const float4*)&x[(size_t)j * DD + lane * 4];
    const float4 xd = *(const float4*)&x[(size_t)d * DD + lane * 4];
    float s = xj.x * uv.x + xj.y * uv.y + xj.z * uv.z + xj.w * uv.w +
              xd.x * vv.x + xd.y * vv.y + xd.z * vv.z + xd.w * vv.w;
#pragma unroll
    for (int off = 32; off; off >>= 1) s += __shfl_xor(s, off);
    const float coef = (s > 0.f) ? 1.f : (1.f / 8192.f);
    h.x = fmaf(coef, xd.x, h.x);
    h.y = fmaf(coef, xd.y, h.y);
    h.z = fmaf(coef, xd.z, h.z);
    h.w = fmaf(coef, xd.w, h.w);
  }
  ushort4 pk;
  pk.x = f2bf(h.x); pk.y = f2bf(h.y); pk.z = f2bf(h.z); pk.w = f2bf(h.w);
  *(ushort4*)&y[(size_t)j * DD + lane * 4] = pk;
}

// ---------------------------------------------------------------------------
// gemm: out = leaky_relu( y_bf16 @ bf16(W)^T ), f32 accum via mfma 16x16x32.
// 128x64 tile (Round-4-verified wave layout): 4 waves 2x2, each 64x32,
// acc[4][2]. BK=32, grid 64x4 = 256 blocks. LDS rows padded to 40 shorts.
// ---------------------------------------------------------------------------
#define BM 128
#define BN 64
#define LDAB 40

__global__ __launch_bounds__(256) void gemm_out(
    const unsigned short* __restrict__ Y, const float* __restrict__ W,
    float* __restrict__ out) {
  __shared__ unsigned short As[BM][LDAB];
  __shared__ unsigned short Bs[BN][LDAB];
  const int t = threadIdx.x;
  const int bm = blockIdx.x * BM, bn = blockIdx.y * BN;
  const int lane = t & 63, wid = t >> 6;
  const int wr = wid >> 1, wc = wid & 1;      // wave -> 64-row x 32-col subtile
  const int l15 = lane & 15, l4 = lane >> 4;
  const int arow = t >> 1, ahalf = t & 1;     // A stage: 2 thr/row, 16 shorts each
  const int brow = t >> 2, bseg = t & 3;      // B stage: 4 thr/row, 8 floats each

  f32x4 acc[4][2] = {};

  for (int k0 = 0; k0 < DD; k0 += 32) {
    {  // A: bf16 y, 128 rows x 32 shorts
      const unsigned short* src = &Y[(size_t)(bm + arow) * DD + k0 + ahalf * 16];
      ushort4 w0 = *(const ushort4*)(src);
      ushort4 w1 = *(const ushort4*)(src + 4);
      ushort4 w2 = *(const ushort4*)(src + 8);
      ushort4 w3 = *(const ushort4*)(src + 12);
      *(ushort4*)&As[arow][ahalf * 16]      = w0;
      *(ushort4*)&As[arow][ahalf * 16 + 4]  = w1;
      *(ushort4*)&As[arow][ahalf * 16 + 8]  = w2;
      *(ushort4*)&As[arow][ahalf * 16 + 12] = w3;
    }
    {  // B: f32 W -> bf16, 64 rows x 32 floats
      const float* src = &W[(size_t)(bn + brow) * DD + k0 + bseg * 8];
      float4 f0 = *(const float4*)src;
      float4 f1 = *(const float4*)(src + 4);
      ushort4 p0, p1;
      p0.x = f2bf(f0.x); p0.y = f2bf(f0.y); p0.z = f2bf(f0.z); p0.w = f2bf(f0.w);
      p1.x = f2bf(f1.x); p1.y = f2bf(f1.y); p1.z = f2bf(f1.z); p1.w = f2bf(f1.w);
      *(ushort4*)&Bs[brow][bseg * 8] = p0;
      *(ushort4*)&Bs[brow][bseg * 8 + 4] = p1;
    }
    __syncthreads();

    bf16x8 af[4], bfr[2];
#pragma unroll
    for (int mf = 0; mf < 4; ++mf)
      af[mf] = *(const bf16x8*)&As[wr * 64 + mf * 16 + l15][l4 * 8];
#pragma unroll
    for (int nf = 0; nf < 2; ++nf)
      bfr[nf] = *(const bf16x8*)&Bs[wc * 32 + nf * 16 + l15][l4 * 8];
#pragma unroll
    for (int mf = 0; mf < 4; ++mf)
#pragma unroll
      for (int nf = 0; nf < 2; ++nf)
        acc[mf][nf] = __builtin_amdgcn_mfma_f32_16x16x32_bf16(
            af[mf], bfr[nf], acc[mf][nf], 0, 0, 0);
    __syncthreads();
  }

  // C/D layout (m89): col = lane&15, row = (lane>>4)*4 + reg; fused LeakyReLU
#pragma unroll
  for (int mf = 0; mf < 4; ++mf)
#pragma unroll
    for (int nf = 0; nf < 2; ++nf)
#pragma unroll
      for (int r = 0; r < 4; ++r) {
        const int row = bm + wr * 64 + mf * 16 + l4 * 4 + r;
        const int col = bn + wc * 32 + nf * 16 + l15;
        float hval = acc[mf][nf][r];
        out[(size_t)row * DD + col] = (hval >= 0.f) ? hval : 0.2f * hval;
      }
}

extern "C" void kernel_launch(void* const* d_in, const int* in_sizes, int n_in,
                              void* d_out, int out_size, void* d_ws, size_t ws_size,
                              hipStream_t stream) {
  const float* x = (const float*)d_in[0];
  const float* W = (const float*)d_in[1];
  const float* a = (const float*)d_in[2];
  const int* gov = (const int*)d_in[4];

  float* u = (float*)d_ws;                         // 1 KB
  float* v = u + DD;                               // 1 KB
  int* inv = (int*)(v + DD);                       // 32 KB
  unsigned short* y = (unsigned short*)(inv + NN); // 4 MB bf16

  hipLaunchKernelGGL(prep, dim3(1), dim3(1024), 0, stream, W, a, gov, u, v, inv);
  hipLaunchKernelGGL(combine, dim3(NN / 4), dim3(256), 0, stream,
                     x, u, v, gov, inv, y);
  hipLaunchKernelGGL(gemm_out, dim3(NN / BM, DD / BN), dim3(256), 0, stream,
                     y, W, (float*)d_out);
}